// Round 14
// baseline (195.665 us; speedup 1.0000x reference)
//
#include <hip/hip_runtime.h>
#include <hip/hip_fp16.h>

#define NDIM 8192
#define KDIM 8192
#define NT 256          // N / 32 hash tiles
#define MOD2 4193281    // HASH_SIZE - 32*32 + 1
#define PRIME 2038074743LL

#define BM 256
#define BN 128
#define BK 32
#define KITER 64        // (KDIM/4)/BK, split-K = 4
#define BSLAB 1032      // halves per k-octet slab (128*8 + 8 pad; phase-balanced)

typedef _Float16 half8 __attribute__((ext_vector_type(8)));
typedef float floatx4 __attribute__((ext_vector_type(4)));

// ---------------- fused prepass: cvt fp32->f16, out=bias, ROBE-Z starts ----------------
__global__ __launch_bounds__(256) void prep_kernel(const float* __restrict__ x,
                                                   const float* __restrict__ hw,
                                                   const float* __restrict__ bias,
                                                   const int* __restrict__ rn,
                                                   __half* __restrict__ xh,
                                                   __half* __restrict__ hh,
                                                   int* __restrict__ starts,
                                                   float* __restrict__ out) {
    int b = blockIdx.x;
    int tid = threadIdx.x;
    if (b < 8192) {                       // cvt: 2M threads x 4 floats
        int i = b * 256 + tid;
        const float4* s; __half2* d; int j;
        if (i < (1 << 20)) { s = (const float4*)x;  d = (__half2*)xh; j = i; }
        else               { s = (const float4*)hw; d = (__half2*)hh; j = i - (1 << 20); }
        float4 v = s[j];
        d[j * 2]     = __floats2half2_rn(v.x, v.y);
        d[j * 2 + 1] = __floats2half2_rn(v.z, v.w);
    } else if (b < 8192 + 4096) {         // init: out = bias (atomic targets)
        int i = (b - 8192) * 256 + tid;
        float4 bv = *(const float4*)(bias + ((i & 2047) << 2));
        ((float4*)out)[i] = bv;
    } else {                              // starts: 64K hash tile offsets
        int t = (b - 12288) * 256 + tid;
        bool is64 = (rn[1] == 0 && rn[3] == 0);   // int64 input: words 1,3 are hi-halves
        long long R1 = is64 ? rn[2] : rn[1];
        long long R2 = is64 ? rn[4] : rn[2];
        long long R3 = is64 ? rn[6] : rn[3];
        long long k_id = t >> 8, n_id = t & 255;
        long long v = (k_id * R3 + n_id * R2 + R1) % PRIME;
        starts[t] = (int)(v % MOD2);
    }
}

// async global->LDS, 16B per lane; LDS dest = wave-uniform base + lane*16 (HW)
__device__ __forceinline__ void gload16(const __half* g, __half* l) {
    __builtin_amdgcn_global_load_lds((const __attribute__((address_space(1))) void*)g,
                                     (__attribute__((address_space(3))) void*)l, 16, 0, 0);
}

#define SBAR() __builtin_amdgcn_sched_barrier(0)
// s_waitcnt encodings (gfx9): lgkmcnt(0) only (vmcnt=63 expcnt=7) = 0xC07F
#define WAIT_LGKM0() __builtin_amdgcn_s_waitcnt(0xC07F)

// ---------------- main GEMM: split-K=4, 256x128 block, 3-buffer deep pipeline ----------------
// R12 phase shape (112.5us) deepened: TRIPLE-buffered LDS (74.9KB, free at the
// grid-capped 2 blocks/CU), staging issued dist-2 -> steady-state vmcnt(6)
// in flight (m201 pattern); STAGE_A gets ~2 phases of slack (was 0.5), B-gathers
// 2 phases (was 1). No vmcnt drain anywhere in the steady loop: STORET's implicit
// register-wait (vmcnt<=6) drains the 1-phase-older STAGE_A (issue order pinned
// by SBAR between STAGE_A and LOADT); end barrier is lgkmcnt(0)-only.
__global__ __launch_bounds__(512, 4) void gemm_kernel(
    const __half* __restrict__ xh, const __half* __restrict__ hh,
    const int* __restrict__ starts, float* __restrict__ out) {
    __shared__ __align__(16) __half As[3][BM * 32];        // 49.2 KB : [m][k] swizzled chunks
    __shared__ __align__(16) __half Bs[3][4 * BSLAB];      // 24.8 KB : [k-oct][n][8] swizzled
    __shared__ int Ss[KITER * 4];                          // 1 KB

    const int tid = threadIdx.x;
    const int lane = tid & 63;
    const int wave = tid >> 6;       // 0..7
    const int wm = wave >> 1;        // 0..3 : 64-row strip
    const int wn = wave & 1;         // 0..1 : 64-col strip
    const int quad = lane >> 4;
    const int l16 = lane & 15;

    const int i = blockIdx.x;        // 512 blocks
    const int ks = i & 3;
    const int m_blk = (i >> 2) & 1;
    const int n_blk = i >> 3;        // 0..63
    const int gm0 = m_blk * BM;
    const int gn0 = n_blk * BN;
    const int kt0 = ks * KITER;
    const int n_id0 = n_blk * 4;     // 4 hash tiles per block

    if (tid < KITER * 4) {
        int kp = tid >> 2, tile = tid & 3;
        Ss[tid] = starts[(kt0 + kp) * NT + n_id0 + tile];
    }

    // ---- A staging via global_load_lds: wave t covers rows t*16..t*16+15 per instr ----
    const int a_t = wave * 2;                              // first of this wave's 2 instrs
    const int a_chunk = (lane & 3) ^ ((lane >> 3) & 3);    // swizzled global chunk
    const __half* a_g0 = xh + (size_t)(gm0 + a_t * 16 + (lane >> 2)) * KDIM
                         + kt0 * 32 + a_chunk * 8;
    const __half* a_g1 = a_g0 + (size_t)16 * KDIM;         // rows +16

#define STAGE_A(c_, kp_) do {                                                  \
        gload16(a_g0 + (kp_) * 32, &As[c_][a_t * 512]);                        \
        gload16(a_g1 + (kp_) * 32, &As[c_][a_t * 512 + 512]);                  \
    } while (0)

    // ---- B staging (reg-staged pack, swizzled; R6-verbatim data path) ----
    const int b_tile = tid >> 7;              // 0..3
    const int t7 = tid & 127;
    const int b_np = t7 & 15;                 // n-pair
    const int b_kg = t7 >> 4;                 // 0..7 : 4-k group
    const int b_oct = b_kg >> 1;
    const unsigned b_base = b_oct * BSLAB;
    const unsigned b_pos = (b_tile * 32 + 2 * b_np) * 8 + (b_kg & 1) * 4;
    const unsigned bswz = (b_np & 4) << 1;    // = (n_even & 8)

    unsigned pbA0, pbA1, pbA2, pbA3, pbB0, pbB1, pbB2, pbB3;

#define LOADT(Q0, Q1, Q2, Q3, kp_) do {                                        \
        int st = Ss[(kp_) * 4 + b_tile];                                       \
        const __half* src = hh + st + b_kg * 128 + b_np * 2;                   \
        Q0 = *(const unsigned*)(src);                                          \
        Q1 = *(const unsigned*)(src + 32);                                     \
        Q2 = *(const unsigned*)(src + 64);                                     \
        Q3 = *(const unsigned*)(src + 96);                                     \
    } while (0)

#define STORET(Q0, Q1, Q2, Q3, c_) do {                                        \
        unsigned lo0 = (Q0 & 0xffffu) | (Q1 << 16);                            \
        unsigned lo1 = (Q2 & 0xffffu) | (Q3 << 16);                            \
        unsigned hi0 = (Q0 >> 16) | (Q1 & 0xffff0000u);                        \
        unsigned hi1 = (Q2 >> 16) | (Q3 & 0xffff0000u);                        \
        uint2 e = {lo0, lo1}, o = {hi0, hi1};                                  \
        *(uint2*)&Bs[c_][b_base + (b_pos ^ bswz)] = e;                         \
        *(uint2*)&Bs[c_][b_base + ((b_pos + 8) ^ bswz)] = o;                   \
    } while (0)

    floatx4 acc[4][4];
#pragma unroll
    for (int r = 0; r < 4; r++)
#pragma unroll
        for (int c = 0; c < 4; c++)
            acc[r][c] = (floatx4){0.f, 0.f, 0.f, 0.f};

    const unsigned rswz = (unsigned)(l16 & 8);          // B read swizzle
    const unsigned a_rswz = (unsigned)((l16 >> 1) & 3); // A read chunk swizzle

    half8 fa0, fa1, fa2, fa3, fb0, fb1, fb2, fb3;       // frags live across mid-barrier

#define READF(c_) do {                                                         \
        fa0 = *(const half8*)&As[c_][(unsigned)(wm * 64 +  0 + l16) * 32 + ((quad ^ a_rswz) * 8)]; \
        fa1 = *(const half8*)&As[c_][(unsigned)(wm * 64 + 16 + l16) * 32 + ((quad ^ a_rswz) * 8)]; \
        fa2 = *(const half8*)&As[c_][(unsigned)(wm * 64 + 32 + l16) * 32 + ((quad ^ a_rswz) * 8)]; \
        fa3 = *(const half8*)&As[c_][(unsigned)(wm * 64 + 48 + l16) * 32 + ((quad ^ a_rswz) * 8)]; \
        fb0 = *(const half8*)&Bs[c_][quad * BSLAB + ((unsigned)((wn * 64 +  0 + l16) * 8) ^ rswz)]; \
        fb1 = *(const half8*)&Bs[c_][quad * BSLAB + ((unsigned)((wn * 64 + 16 + l16) * 8) ^ rswz)]; \
        fb2 = *(const half8*)&Bs[c_][quad * BSLAB + ((unsigned)((wn * 64 + 32 + l16) * 8) ^ rswz)]; \
        fb3 = *(const half8*)&Bs[c_][quad * BSLAB + ((unsigned)((wn * 64 + 48 + l16) * 8) ^ rswz)]; \
    } while (0)

#define MFMAC() do {                                                           \
        __builtin_amdgcn_s_setprio(1);                                         \
        acc[0][0] = __builtin_amdgcn_mfma_f32_16x16x32_f16(fa0, fb0, acc[0][0], 0, 0, 0); \
        acc[1][0] = __builtin_amdgcn_mfma_f32_16x16x32_f16(fa1, fb0, acc[1][0], 0, 0, 0); \
        acc[2][0] = __builtin_amdgcn_mfma_f32_16x16x32_f16(fa2, fb0, acc[2][0], 0, 0, 0); \
        acc[3][0] = __builtin_amdgcn_mfma_f32_16x16x32_f16(fa3, fb0, acc[3][0], 0, 0, 0); \
        acc[0][1] = __builtin_amdgcn_mfma_f32_16x16x32_f16(fa0, fb1, acc[0][1], 0, 0, 0); \
        acc[1][1] = __builtin_amdgcn_mfma_f32_16x16x32_f16(fa1, fb1, acc[1][1], 0, 0, 0); \
        acc[2][1] = __builtin_amdgcn_mfma_f32_16x16x32_f16(fa2, fb1, acc[2][1], 0, 0, 0); \
        acc[3][1] = __builtin_amdgcn_mfma_f32_16x16x32_f16(fa3, fb1, acc[3][1], 0, 0, 0); \
        acc[0][2] = __builtin_amdgcn_mfma_f32_16x16x32_f16(fa0, fb2, acc[0][2], 0, 0, 0); \
        acc[1][2] = __builtin_amdgcn_mfma_f32_16x16x32_f16(fa1, fb2, acc[1][2], 0, 0, 0); \
        acc[2][2] = __builtin_amdgcn_mfma_f32_16x16x32_f16(fa2, fb2, acc[2][2], 0, 0, 0); \
        acc[3][2] = __builtin_amdgcn_mfma_f32_16x16x32_f16(fa3, fb2, acc[3][2], 0, 0, 0); \
        acc[0][3] = __builtin_amdgcn_mfma_f32_16x16x32_f16(fa0, fb3, acc[0][3], 0, 0, 0); \
        acc[1][3] = __builtin_amdgcn_mfma_f32_16x16x32_f16(fa1, fb3, acc[1][3], 0, 0, 0); \
        acc[2][3] = __builtin_amdgcn_mfma_f32_16x16x32_f16(fa2, fb3, acc[2][3], 0, 0, 0); \
        acc[3][3] = __builtin_amdgcn_mfma_f32_16x16x32_f16(fa3, fb3, acc[3][3], 0, 0, 0); \
        __builtin_amdgcn_s_setprio(0);                                         \
    } while (0)

    // rotating buffer indices: ca=consume, cb=next (fully staged), cc=being staged
    unsigned ca = 0, cb = 1, cc = 2, ct;
#define ROT() do { ct = ca; ca = cb; cb = cc; cc = ct; } while (0)

    __syncthreads();                  // Ss visible
    STAGE_A(0, 0);                    // tile 0 A -> buf0
    SBAR();
    LOADT(pbA0, pbA1, pbA2, pbA3, 0); // tile 0 B -> set A
    STAGE_A(1, 1);                    // tile 1 A -> buf1
    SBAR();
    LOADT(pbB0, pbB1, pbB2, pbB3, 1); // tile 1 B -> set B
    STORET(pbA0, pbA1, pbA2, pbA3, 0);  // implicit wait drains STAGE_A(0)+LOADT(0)
    __syncthreads();                  // full drain: buf0 complete, buf1 A landed, sB ready

    for (int kp = 0; kp < KITER; kp += 2) {
        // ---- phase even: consume buf ca (tile kp); stage tile kp+2 into cc ----
        READF(ca);
        if (kp + 2 < KITER) {
            STAGE_A(cc, kp + 2);
            SBAR();                                  // pin queue order: A-gloads older
            LOADT(pbA0, pbA1, pbA2, pbA3, kp + 2);
        }
        SBAR();
        __builtin_amdgcn_s_barrier();                // rendezvous: hide ds_read latency
        SBAR();
        MFMAC();
        STORET(pbB0, pbB1, pbB2, pbB3, cb);          // tile kp+1 B -> cb (implicit vmcnt<=6
                                                     // drains STAGE_A(kp+1), issued 1 phase ago)
        SBAR();
        WAIT_LGKM0();                                // ds_writes visible; no vmcnt drain
        __builtin_amdgcn_s_barrier();
        SBAR();
        ROT();

        // ---- phase odd: consume buf ca (tile kp+1); stage tile kp+3 into cc ----
        READF(ca);
        if (kp + 3 < KITER) {
            STAGE_A(cc, kp + 3);
            SBAR();
            LOADT(pbB0, pbB1, pbB2, pbB3, kp + 3);
        }
        SBAR();
        __builtin_amdgcn_s_barrier();
        SBAR();
        MFMAC();
        if (kp + 2 < KITER)
            STORET(pbA0, pbA1, pbA2, pbA3, cb);      // tile kp+2 B -> cb
        SBAR();
        WAIT_LGKM0();
        __builtin_amdgcn_s_barrier();
        SBAR();
        ROT();
    }

    // ---- epilogue: atomic accumulate (C/D layout col=lane&15, row=quad*4+reg) ----
#pragma unroll
    for (int c = 0; c < 4; c++) {
        int col = gn0 + wn * 64 + c * 16 + l16;
#pragma unroll
        for (int r = 0; r < 4; r++) {
            int row0 = gm0 + wm * 64 + r * 16 + quad * 4;
#pragma unroll
            for (int e = 0; e < 4; e++)
                atomicAdd(&out[(size_t)(row0 + e) * NDIM + col], acc[r][c][e]);
        }
    }
#undef LOADT
#undef STORET
#undef READF
#undef MFMAC
#undef STAGE_A
#undef ROT
}

extern "C" void kernel_launch(void* const* d_in, const int* in_sizes, int n_in,
                              void* d_out, int out_size, void* d_ws, size_t ws_size,
                              hipStream_t stream) {
    const float* x = (const float*)d_in[0];
    const float* hw = (const float*)d_in[1];
    const float* bias = (const float*)d_in[2];
    const int* rn = (const int*)d_in[3];
    float* out = (float*)d_out;

    char* ws = (char*)d_ws;
    __half* xh = (__half*)ws;                          // 8 MB : x as f16
    __half* hh = (__half*)(ws + (8u << 20));           // 8 MB : hashed_weight as f16
    int* starts = (int*)(ws + (16u << 20));            // 256 KB : tile start table

    hipLaunchKernelGGL(prep_kernel, dim3(12544), dim3(256), 0, stream,
                       x, hw, bias, rn, xh, hh, starts, out);
    hipLaunchKernelGGL(gemm_kernel, dim3(512), dim3(512), 0, stream, xh, hh, starts, out);
}

// Round 15
// 191.788 us; speedup vs baseline: 1.0202x; 1.0202x over previous
//
#include <hip/hip_runtime.h>
#include <hip/hip_fp16.h>

#define NDIM 8192
#define KDIM 8192
#define NT 256          // N / 32 hash tiles
#define MOD2 4193281    // HASH_SIZE - 32*32 + 1
#define PRIME 2038074743LL

#define BM 256
#define BN 128
#define BK 32
#define KITER 64        // (KDIM/4)/BK, split-K = 4
#define BSLAB 1032      // halves per k-octet slab (128*8 + 8 pad; phase-balanced)

typedef _Float16 half8 __attribute__((ext_vector_type(8)));
typedef float floatx4 __attribute__((ext_vector_type(4)));

// ---------------- fused prepass: cvt fp32->f16, out=bias, ROBE-Z starts ----------------
__global__ __launch_bounds__(256) void prep_kernel(const float* __restrict__ x,
                                                   const float* __restrict__ hw,
                                                   const float* __restrict__ bias,
                                                   const int* __restrict__ rn,
                                                   __half* __restrict__ xh,
                                                   __half* __restrict__ hh,
                                                   int* __restrict__ starts,
                                                   float* __restrict__ out) {
    int b = blockIdx.x;
    int tid = threadIdx.x;
    if (b < 8192) {                       // cvt: 2M threads x 4 floats
        int i = b * 256 + tid;
        const float4* s; __half2* d; int j;
        if (i < (1 << 20)) { s = (const float4*)x;  d = (__half2*)xh; j = i; }
        else               { s = (const float4*)hw; d = (__half2*)hh; j = i - (1 << 20); }
        float4 v = s[j];
        d[j * 2]     = __floats2half2_rn(v.x, v.y);
        d[j * 2 + 1] = __floats2half2_rn(v.z, v.w);
    } else if (b < 8192 + 4096) {         // init: out = bias (atomic targets)
        int i = (b - 8192) * 256 + tid;
        float4 bv = *(const float4*)(bias + ((i & 2047) << 2));
        ((float4*)out)[i] = bv;
    } else {                              // starts: 64K hash tile offsets
        int t = (b - 12288) * 256 + tid;
        bool is64 = (rn[1] == 0 && rn[3] == 0);   // int64 input: words 1,3 are hi-halves
        long long R1 = is64 ? rn[2] : rn[1];
        long long R2 = is64 ? rn[4] : rn[2];
        long long R3 = is64 ? rn[6] : rn[3];
        long long k_id = t >> 8, n_id = t & 255;
        long long v = (k_id * R3 + n_id * R2 + R1) % PRIME;
        starts[t] = (int)(v % MOD2);
    }
}

// async global->LDS, 16B per lane; LDS dest = wave-uniform base + lane*16 (HW)
__device__ __forceinline__ void gload16(const __half* g, __half* l) {
    __builtin_amdgcn_global_load_lds((const __attribute__((address_space(1))) void*)g,
                                     (__attribute__((address_space(3))) void*)l, 16, 0, 0);
}

#define SBAR() __builtin_amdgcn_sched_barrier(0)

// ---------------- main GEMM: split-K=4, 256x128 block, 4 waves x (128x64) tiles --------
// LDS-traffic reduction: 12 ds_read_b128 per 32 MFMAs per wave (0.375 reads/MFMA,
// was 0.5 at 8x(64x64)). R12's proven double-buffer phase skeleton; counted waits
// re-derived for STAGE_A=4 instrs, LOADT=8 loads: steady vmcnt(8), tail vmcnt(0).
__global__ __launch_bounds__(256, 2) void gemm_kernel(
    const __half* __restrict__ xh, const __half* __restrict__ hh,
    const int* __restrict__ starts, float* __restrict__ out) {
    __shared__ __align__(16) __half As[2][BM * 32];        // 32 KB : [m][k] swizzled chunks
    __shared__ __align__(16) __half Bs[2][4 * BSLAB];      // 16.5 KB : [k-oct][n][8] swizzled
    __shared__ int Ss[KITER * 4];                          // 1 KB

    const int tid = threadIdx.x;
    const int lane = tid & 63;
    const int wave = tid >> 6;       // 0..3
    const int wm = wave >> 1;        // 0..1 : 128-row strip
    const int wn = wave & 1;         // 0..1 : 64-col strip
    const int quad = lane >> 4;
    const int l16 = lane & 15;

    const int i = blockIdx.x;        // 512 blocks
    const int ks = i & 3;
    const int m_blk = (i >> 2) & 1;
    const int n_blk = i >> 3;        // 0..63
    const int gm0 = m_blk * BM;
    const int gn0 = n_blk * BN;
    const int kt0 = ks * KITER;
    const int n_id0 = n_blk * 4;     // 4 hash tiles per block

    {   // 256 threads cover all KITER*4 = 256 entries
        int kp = tid >> 2, tile = tid & 3;
        Ss[tid] = starts[(kt0 + kp) * NT + n_id0 + tile];
    }

    // ---- A staging via global_load_lds: wave covers rows wave*64..+63 via 4 instrs ----
    const int a_w4 = wave * 4;                             // first 16-row group of this wave
    const int a_chunk = (lane & 3) ^ ((lane >> 3) & 3);    // swizzled global chunk
    const __half* a_g0 = xh + (size_t)(gm0 + a_w4 * 16 + (lane >> 2)) * KDIM
                         + kt0 * 32 + a_chunk * 8;
    const __half* a_g1 = a_g0 + (size_t)16 * KDIM;
    const __half* a_g2 = a_g0 + (size_t)32 * KDIM;
    const __half* a_g3 = a_g0 + (size_t)48 * KDIM;

#define STAGE_A(c_, kp_) do {                                                  \
        gload16(a_g0 + (kp_) * 32, &As[c_][a_w4 * 512]);                       \
        gload16(a_g1 + (kp_) * 32, &As[c_][a_w4 * 512 + 512]);                 \
        gload16(a_g2 + (kp_) * 32, &As[c_][a_w4 * 512 + 1024]);                \
        gload16(a_g3 + (kp_) * 32, &As[c_][a_w4 * 512 + 1536]);                \
    } while (0)

    // ---- B staging: 64 threads per 32x32 hash tile; thread covers 2n x 8k (R4-verified) ----
    const int b_tile = tid >> 6;              // 0..3
    const int t6 = tid & 63;
    const int b_np = t6 & 15;                 // n-pair
    const int b_kg = t6 >> 4;                 // 0..3 : low 4-k group (also covers b_kg+4)
    const int b_oct = b_kg >> 1;
    const unsigned b_base = b_oct * BSLAB;
    const unsigned b_pos = (b_tile * 32 + 2 * b_np) * 8 + (b_kg & 1) * 4;
    const unsigned bswz = (b_np & 4) << 1;    // = (n_even & 8)

    unsigned pbA0, pbA1, pbA2, pbA3, pbA4, pbA5, pbA6, pbA7;
    unsigned pbB0, pbB1, pbB2, pbB3, pbB4, pbB5, pbB6, pbB7;

#define LOADT(Q0, Q1, Q2, Q3, Q4, Q5, Q6, Q7, kp_) do {                        \
        int st = Ss[(kp_) * 4 + b_tile];                                       \
        const __half* src = hh + st + b_kg * 128 + b_np * 2;                   \
        Q0 = *(const unsigned*)(src);                                          \
        Q1 = *(const unsigned*)(src + 32);                                     \
        Q2 = *(const unsigned*)(src + 64);                                     \
        Q3 = *(const unsigned*)(src + 96);                                     \
        Q4 = *(const unsigned*)(src + 512);                                    \
        Q5 = *(const unsigned*)(src + 544);                                    \
        Q6 = *(const unsigned*)(src + 576);                                    \
        Q7 = *(const unsigned*)(src + 608);                                    \
    } while (0)

#define STORET(Q0, Q1, Q2, Q3, Q4, Q5, Q6, Q7, c_) do {                        \
        unsigned lo0 = (Q0 & 0xffffu) | (Q1 << 16);                            \
        unsigned lo1 = (Q2 & 0xffffu) | (Q3 << 16);                            \
        unsigned hi0 = (Q0 >> 16) | (Q1 & 0xffff0000u);                        \
        unsigned hi1 = (Q2 >> 16) | (Q3 & 0xffff0000u);                        \
        uint2 e0 = {lo0, lo1}, o0 = {hi0, hi1};                                \
        *(uint2*)&Bs[c_][b_base + (b_pos ^ bswz)] = e0;                        \
        *(uint2*)&Bs[c_][b_base + ((b_pos + 8) ^ bswz)] = o0;                  \
        unsigned lo2 = (Q4 & 0xffffu) | (Q5 << 16);                            \
        unsigned lo3 = (Q6 & 0xffffu) | (Q7 << 16);                            \
        unsigned hi2 = (Q4 >> 16) | (Q5 & 0xffff0000u);                        \
        unsigned hi3 = (Q6 >> 16) | (Q7 & 0xffff0000u);                        \
        uint2 e1 = {lo2, lo3}, o1 = {hi2, hi3};                                \
        *(uint2*)&Bs[c_][b_base + 2 * BSLAB + (b_pos ^ bswz)] = e1;            \
        *(uint2*)&Bs[c_][b_base + 2 * BSLAB + ((b_pos + 8) ^ bswz)] = o1;      \
    } while (0)

    floatx4 acc[8][4];
#pragma unroll
    for (int r = 0; r < 8; r++)
#pragma unroll
        for (int c = 0; c < 4; c++)
            acc[r][c] = (floatx4){0.f, 0.f, 0.f, 0.f};

    const unsigned rswz = (unsigned)(l16 & 8);          // B read swizzle
    const unsigned a_rswz = (unsigned)((l16 >> 1) & 3); // A read chunk swizzle

    half8 fa0, fa1, fa2, fa3, fa4, fa5, fa6, fa7, fb0, fb1, fb2, fb3;

#define READF(c_) do {                                                         \
        fa0 = *(const half8*)&As[c_][(unsigned)(wm * 128 +   0 + l16) * 32 + ((quad ^ a_rswz) * 8)]; \
        fa1 = *(const half8*)&As[c_][(unsigned)(wm * 128 +  16 + l16) * 32 + ((quad ^ a_rswz) * 8)]; \
        fa2 = *(const half8*)&As[c_][(unsigned)(wm * 128 +  32 + l16) * 32 + ((quad ^ a_rswz) * 8)]; \
        fa3 = *(const half8*)&As[c_][(unsigned)(wm * 128 +  48 + l16) * 32 + ((quad ^ a_rswz) * 8)]; \
        fa4 = *(const half8*)&As[c_][(unsigned)(wm * 128 +  64 + l16) * 32 + ((quad ^ a_rswz) * 8)]; \
        fa5 = *(const half8*)&As[c_][(unsigned)(wm * 128 +  80 + l16) * 32 + ((quad ^ a_rswz) * 8)]; \
        fa6 = *(const half8*)&As[c_][(unsigned)(wm * 128 +  96 + l16) * 32 + ((quad ^ a_rswz) * 8)]; \
        fa7 = *(const half8*)&As[c_][(unsigned)(wm * 128 + 112 + l16) * 32 + ((quad ^ a_rswz) * 8)]; \
        fb0 = *(const half8*)&Bs[c_][quad * BSLAB + ((unsigned)((wn * 64 +  0 + l16) * 8) ^ rswz)]; \
        fb1 = *(const half8*)&Bs[c_][quad * BSLAB + ((unsigned)((wn * 64 + 16 + l16) * 8) ^ rswz)]; \
        fb2 = *(const half8*)&Bs[c_][quad * BSLAB + ((unsigned)((wn * 64 + 32 + l16) * 8) ^ rswz)]; \
        fb3 = *(const half8*)&Bs[c_][quad * BSLAB + ((unsigned)((wn * 64 + 48 + l16) * 8) ^ rswz)]; \
    } while (0)

#define MF(r_, c_, fa_, fb_) \
        acc[r_][c_] = __builtin_amdgcn_mfma_f32_16x16x32_f16(fa_, fb_, acc[r_][c_], 0, 0, 0)

#define MFMAC() do {                                                           \
        __builtin_amdgcn_s_setprio(1);                                         \
        MF(0,0,fa0,fb0); MF(1,0,fa1,fb0); MF(2,0,fa2,fb0); MF(3,0,fa3,fb0);    \
        MF(4,0,fa4,fb0); MF(5,0,fa5,fb0); MF(6,0,fa6,fb0); MF(7,0,fa7,fb0);    \
        MF(0,1,fa0,fb1); MF(1,1,fa1,fb1); MF(2,1,fa2,fb1); MF(3,1,fa3,fb1);    \
        MF(4,1,fa4,fb1); MF(5,1,fa5,fb1); MF(6,1,fa6,fb1); MF(7,1,fa7,fb1);    \
        MF(0,2,fa0,fb2); MF(1,2,fa1,fb2); MF(2,2,fa2,fb2); MF(3,2,fa3,fb2);    \
        MF(4,2,fa4,fb2); MF(5,2,fa5,fb2); MF(6,2,fa6,fb2); MF(7,2,fa7,fb2);    \
        MF(0,3,fa0,fb3); MF(1,3,fa1,fb3); MF(2,3,fa2,fb3); MF(3,3,fa3,fb3);    \
        MF(4,3,fa4,fb3); MF(5,3,fa5,fb3); MF(6,3,fa6,fb3); MF(7,3,fa7,fb3);    \
        __builtin_amdgcn_s_setprio(0);                                         \
    } while (0)

    __syncthreads();                  // Ss visible
    STAGE_A(0, 0);                    // tile 0 A -> buf0 (4 gloads)
    SBAR();
    LOADT(pbA0, pbA1, pbA2, pbA3, pbA4, pbA5, pbA6, pbA7, 0);
    LOADT(pbB0, pbB1, pbB2, pbB3, pbB4, pbB5, pbB6, pbB7, 1);
    STORET(pbA0, pbA1, pbA2, pbA3, pbA4, pbA5, pbA6, pbA7, 0);
    __syncthreads();                  // full drain: buf0 complete

    for (int kp = 0; kp < KITER; kp += 2) {
        // ---- phase even: tile kp (buf0); stage A(kp+1)->buf1, prefetch B(kp+2) ----
        READF(0);
        STAGE_A(1, kp + 1);
        SBAR();                                     // pin queue order: A-gloads older
        if (kp + 2 < KITER)
            LOADT(pbA0, pbA1, pbA2, pbA3, pbA4, pbA5, pbA6, pbA7, kp + 2);
        SBAR();
        __builtin_amdgcn_s_barrier();               // rendezvous: hide ds_read latency
        SBAR();
        MFMAC();
        STORET(pbB0, pbB1, pbB2, pbB3, pbB4, pbB5, pbB6, pbB7, 1);
        SBAR();
        if (kp + 2 < KITER)
            __builtin_amdgcn_s_waitcnt(0x0078);     // vmcnt(8) lgkm(0): drain STAGE_A,
                                                    // keep 8 B-gathers in flight
        else
            __builtin_amdgcn_s_waitcnt(0x0070);     // TAIL: vmcnt(0) (no younger loads)
        __builtin_amdgcn_s_barrier();
        SBAR();

        // ---- phase odd: tile kp+1 (buf1); stage A(kp+2)->buf0, prefetch B(kp+3) ----
        READF(1);
        if (kp + 2 < KITER) STAGE_A(0, kp + 2);
        SBAR();
        if (kp + 3 < KITER)
            LOADT(pbB0, pbB1, pbB2, pbB3, pbB4, pbB5, pbB6, pbB7, kp + 3);
        SBAR();
        __builtin_amdgcn_s_barrier();
        SBAR();
        MFMAC();
        if (kp + 2 < KITER)
            STORET(pbA0, pbA1, pbA2, pbA3, pbA4, pbA5, pbA6, pbA7, 0);
        SBAR();
        __builtin_amdgcn_s_waitcnt(0x0078);         // vmcnt(8) lgkm(0)
        __builtin_amdgcn_s_barrier();
        SBAR();
    }

    // ---- epilogue: atomic accumulate (C/D layout col=lane&15, row=quad*4+reg) ----
#pragma unroll
    for (int c = 0; c < 4; c++) {
        int col = gn0 + wn * 64 + c * 16 + l16;
#pragma unroll
        for (int r = 0; r < 8; r++) {
            int row0 = gm0 + wm * 128 + r * 16 + quad * 4;
#pragma unroll
            for (int e = 0; e < 4; e++)
                atomicAdd(&out[(size_t)(row0 + e) * NDIM + col], acc[r][c][e]);
        }
    }
#undef LOADT
#undef STORET
#undef READF
#undef MFMAC
#undef MF
#undef STAGE_A
}

extern "C" void kernel_launch(void* const* d_in, const int* in_sizes, int n_in,
                              void* d_out, int out_size, void* d_ws, size_t ws_size,
                              hipStream_t stream) {
    const float* x = (const float*)d_in[0];
    const float* hw = (const float*)d_in[1];
    const float* bias = (const float*)d_in[2];
    const int* rn = (const int*)d_in[3];
    float* out = (float*)d_out;

    char* ws = (char*)d_ws;
    __half* xh = (__half*)ws;                          // 8 MB : x as f16
    __half* hh = (__half*)(ws + (8u << 20));           // 8 MB : hashed_weight as f16
    int* starts = (int*)(ws + (16u << 20));            // 256 KB : tile start table

    hipLaunchKernelGGL(prep_kernel, dim3(12544), dim3(256), 0, stream,
                       x, hw, bias, rn, xh, hh, starts, out);
    hipLaunchKernelGGL(gemm_kernel, dim3(512), dim3(256), 0, stream, xh, hh, starts, out);
}